// Round 12
// baseline (141.733 us; speedup 1.0000x reference)
//
#include <hip/hip_runtime.h>
#include <hip/hip_bf16.h>

#define BB 8
#define NN 8192
#define MM 2048
#define C1 64
#define C2 128
#define CIN 192
#define CO 128
#define NB (BB*NN)
#define EPS 1e-5f

#define PRE_ARGMIN 1024
#define PRE_PREPH  (PRE_ARGMIN + 512)
#define PRE_TOTAL  (PRE_PREPH + 96)

typedef unsigned short u16;
typedef unsigned int u32;
typedef __bf16 bf16_t;
typedef bf16_t bf16x8 __attribute__((ext_vector_type(8)));
typedef float f32x4 __attribute__((ext_vector_type(4)));
typedef float f32x2 __attribute__((ext_vector_type(2)));

static __device__ __forceinline__ float b2f(u16 u) { return __uint_as_float(((u32)u) << 16); }
static __device__ __forceinline__ u16 f2b(float f) {
    __hip_bfloat16 h = __float2bfloat16(f);
    u16 u; __builtin_memcpy(&u, &h, 2); return u;
}

// ================= k_pre: argmin (SGPR-stream) + high-feats transpose + weight convert =================
__global__ __launch_bounds__(256) void k_pre(
        const float* __restrict__ lt_, const float* __restrict__ lp_,
        const float* __restrict__ ht_, const float* __restrict__ hp_,
        const float* __restrict__ hf, const float* __restrict__ W0, const float* __restrict__ W1,
        int* __restrict__ idx, u16* __restrict__ hT,
        u16* __restrict__ W0b, u16* __restrict__ W1b) {
    __shared__ u16 s_t[64][65];                     // prep_h staging (8.3KB)
    __shared__ float sm_s[256];                     // argmin cross-wave merge
    __shared__ int sm_i[256];
    int bid = blockIdx.x, tid = threadIdx.x;

    if (bid < PRE_ARGMIN) {
        // ---- nearest neighbor: lane = query, candidates via wave-uniform s_load ----
        // Hot loop has NO LDS/VMEM: coords stream through SGPRs (scalar pipe),
        // d2 via v_pk (IEEE rn, bitwise == np's mul,mul,add; x-lt = -(lt-x) exact).
        // Chains keep (last,prev) hits for sqrt-tie (np first-index argmin over sqrt).
        int lane = tid & 63;
        int b = bid >> 7;                           // 128 blocks per batch
        int n0 = (bid & 127) << 6;                  // 64 queries per block
        int w = __builtin_amdgcn_readfirstlane(tid >> 6);     // wave id, uniform
        int cbase = __builtin_amdgcn_readfirstlane(b * MM + (w << 9));
        const float* hx = ht_ + cbase;              // this wave's 512 candidates
        const float* hy = hp_ + cbase;
        float ltv = lt_[b * NN + n0 + lane];
        float lpv = lp_[b * NN + n0 + lane];
        f32x2 nlt2 = {-ltv, -ltv}, nlp2 = {-lpv, -lpv};
        float dl[4] = {1e30f, 1e30f, 1e30f, 1e30f};
        float dpv[4] = {1e30f, 1e30f, 1e30f, 1e30f};
        int il[4] = {0, 0, 0, 0}, ipx[4] = {0, 0, 0, 0};
#pragma unroll 4
        for (int k = 0; k < 64; ++k) {              // chain c scans [c*128, c*128+128)
#pragma unroll
            for (int c = 0; c < 4; ++c) {
                f32x2 xx = *(const f32x2*)&hx[(c << 7) + (k << 1)];   // uniform -> s_load
                f32x2 yy = *(const f32x2*)&hy[(c << 7) + (k << 1)];
                f32x2 dt, dq, t2, u2, d2;
                asm("v_pk_add_f32 %0, %1, %2" : "=v"(dt) : "s"(xx), "v"(nlt2));
                asm("v_pk_add_f32 %0, %1, %2" : "=v"(dq) : "s"(yy), "v"(nlp2));
                asm("v_pk_mul_f32 %0, %1, %2" : "=v"(t2) : "v"(dt), "v"(dt));
                asm("v_pk_mul_f32 %0, %1, %2" : "=v"(u2) : "v"(dq), "v"(dq));
                asm("v_pk_add_f32 %0, %1, %2" : "=v"(d2) : "v"(t2), "v"(u2));
                int i0 = (w << 9) + (c << 7) + (k << 1);
                bool h0 = d2[0] < dl[c];
                dpv[c] = h0 ? dl[c] : dpv[c];
                ipx[c] = h0 ? il[c] : ipx[c];
                dl[c] = h0 ? d2[0] : dl[c];
                il[c] = h0 ? i0 : il[c];
                bool h1 = d2[1] < dl[c];
                dpv[c] = h1 ? dl[c] : dpv[c];
                ipx[c] = h1 ? il[c] : ipx[c];
                dl[c] = h1 ? d2[1] : dl[c];
                il[c] = h1 ? i0 + 1 : il[c];
            }
        }
        float bs = 1e30f; int bm = 0x7fffffff;
#pragma unroll
        for (int c = 0; c < 4; ++c) {               // ascending-c = ascending idx ranges
            float sl = __fsqrt_rn(dl[c]);
            float sp = __fsqrt_rn(dpv[c]);
            int cand = (sp == sl) ? ipx[c] : il[c]; // sqrt-tie promotes earlier hit
            if (sl < bs || (sl == bs && cand < bm)) { bs = sl; bm = cand; }
        }
        sm_s[(w << 6) + lane] = bs;
        sm_i[(w << 6) + lane] = bm;
        __syncthreads();
        if (tid < 64) {                             // merge 4 waves by (sqrt, idx)
            float fb = sm_s[tid]; int fm = sm_i[tid];
#pragma unroll
            for (int w2 = 1; w2 < 4; ++w2) {
                float ov = sm_s[(w2 << 6) + tid];
                int om = sm_i[(w2 << 6) + tid];
                if (ov < fb || (ov == fb && om < fm)) { fb = ov; fm = om; }
            }
            idx[b * NN + n0 + tid] = fm;
        }
    } else if (bid < PRE_PREPH) {
        // ---- high_feats transpose: f32 [B][C2][M] -> bf16 [B][M][C2] ----
        int bid2 = bid - PRE_ARGMIN;
        int b = bid2 >> 6, m0 = ((bid2 >> 1) & 31) * 64, c0 = (bid2 & 1) * 64;
        for (int e = tid; e < 64 * 64; e += 256) {
            int i = e >> 6, j = e & 63;             // i: c, j: m (coalesced in m)
            s_t[i][j] = f2b(hf[(b * C2 + c0 + i) * MM + m0 + j]);
        }
        __syncthreads();
        for (int e = tid; e < 64 * 64; e += 256) {
            int ii = e & 63, jj = e >> 6;           // coalesced in c
            hT[(b * MM + m0 + jj) * C2 + c0 + ii] = s_t[ii][jj];
        }
    } else {
        // ---- weights f32 -> bf16 ----
        int t = (bid - PRE_PREPH) * 256 + tid;
        if (t < CIN * CO) W0b[t] = f2b(W0[t]);
        if (t < CO * CO)  W1b[t] = f2b(W1[t]);
    }
}

// epilogue: bias add, per-channel sum/sumsq into LDS chs/chq, bf16 store to ylds
static __device__ __forceinline__ void epilogue(
        f32x4* ac0, f32x4* ac1, const float* bias, u16* yl,
        float* chs, float* chq, int w, int ln, int q) {
#pragma unroll
    for (int mf = 0; mf < 2; ++mf) {
        f32x4* A = mf ? ac1 : ac0;
        int chb = 32 * w + 16 * mf + 4 * q;
        float bs[4], ss[4] = {0.f, 0.f, 0.f, 0.f}, sq[4] = {0.f, 0.f, 0.f, 0.f};
#pragma unroll
        for (int r = 0; r < 4; ++r) bs[r] = bias[chb + r];
#pragma unroll
        for (int nf = 0; nf < 4; ++nf) {
            int n = (nf << 4) + ln;
#pragma unroll
            for (int r = 0; r < 4; ++r) {
                float y = A[nf][r] + bs[r];
                ss[r] += y; sq[r] += y * y;
                int o = chb + r;
                yl[(o << 6) + (n ^ ((o & 7) << 3))] = f2b(y);
            }
        }
#pragma unroll
        for (int r = 0; r < 4; ++r) {
            float v = ss[r], u2 = sq[r];
#pragma unroll
            for (int d = 1; d < 16; d <<= 1) {
                v += __shfl_xor(v, d, 64);
                u2 += __shfl_xor(u2, d, 64);
            }
            if (ln == 0) { atomicAdd(&chs[chb + r], v); atomicAdd(&chq[chb + r], u2); }
        }
    }
}

// ================= layer 0: gather + MFMA gemm + bias -> y0 (ws, bf16) + stat partials =================
__global__ __launch_bounds__(256) void k_l0(
        const float* __restrict__ lf, const u16* __restrict__ hT, const int* __restrict__ idx,
        const u16* __restrict__ W0b, const float* __restrict__ b0,
        u16* __restrict__ y0, float* __restrict__ gpart) {
    __shared__ u16 xt[64 * CIN];          // B-tile [n][k] XOR-chunk-swizzled (24.5KB)
    __shared__ u16 ylds[CO * 64];         // y tile [o][n swz] (16KB)
    __shared__ float chs[CO], chq[CO];
    __shared__ int idxs[64];
    int tid = threadIdx.x;
    int l = tid & 63, w = tid >> 6, ln = l & 15, q = l >> 4;
    int b = blockIdx.x >> 7, n0 = (blockIdx.x & 127) << 6;
    if (tid < 64) idxs[tid] = idx[b * NN + n0 + tid];
    if (tid < 128) { chs[tid] = 0.f; chq[tid] = 0.f; }
    __syncthreads();
    // stage low_feats rows 0..63 via in-register transpose (lane = channel, f32 -> bf16)
    {
        const float* src = lf + (size_t)(b * C1 + l) * NN + n0 + (w << 4);
        float4 f0 = *(const float4*)src;
        float4 f1 = *(const float4*)(src + 4);
        float4 f2 = *(const float4*)(src + 8);
        float4 f3 = *(const float4*)(src + 12);
        float v[16] = {f0.x, f0.y, f0.z, f0.w, f1.x, f1.y, f1.z, f1.w,
                       f2.x, f2.y, f2.z, f2.w, f3.x, f3.y, f3.z, f3.w};
        int cc = l >> 3, clo = l & 7;
#pragma unroll
        for (int i = 0; i < 16; ++i) {
            int n = (w << 4) + i;
            xt[n * CIN + ((cc ^ (i & 7)) << 3) + clo] = f2b(v[i]);
        }
    }
    // gather nearest high rows (contiguous 256B per row from bf16 hT)
    for (int e = tid; e < 1024; e += 256) {
        int n = e >> 4, c16 = e & 15;
        uint4 v = *(const uint4*)(hT + (size_t)(b * MM + idxs[n]) * C2 + (c16 << 3));
        *(uint4*)&xt[n * CIN + (((8 + c16) ^ (n & 7)) << 3)] = v;
    }
    __syncthreads();
    f32x4 ac0[4], ac1[4];
#pragma unroll
    for (int nf = 0; nf < 4; ++nf) {
        ac0[nf] = f32x4{0.f, 0.f, 0.f, 0.f};
        ac1[nf] = f32x4{0.f, 0.f, 0.f, 0.f};
    }
    const u16* w0r0 = W0b + (32 * w + ln) * CIN + 8 * q;
    const u16* w0r1 = w0r0 + 16 * CIN;
#pragma unroll
    for (int s = 0; s < 6; ++s) {
        bf16x8 a0 = *(const bf16x8*)(w0r0 + 32 * s);
        bf16x8 a1 = *(const bf16x8*)(w0r1 + 32 * s);
#pragma unroll
        for (int nf = 0; nf < 4; ++nf) {
            bf16x8 bv = *(const bf16x8*)&xt[(16 * nf + ln) * CIN + (((4 * s + q) ^ (ln & 7)) << 3)];
            ac0[nf] = __builtin_amdgcn_mfma_f32_16x16x32_bf16(a0, bv, ac0[nf], 0, 0, 0);
            ac1[nf] = __builtin_amdgcn_mfma_f32_16x16x32_bf16(a1, bv, ac1[nf], 0, 0, 0);
        }
    }
    epilogue(ac0, ac1, b0, ylds, chs, chq, w, ln, q);
    __syncthreads();
    // per-block stat partials: unique coalesced slot, plain store (no atomics/fences)
    gpart[blockIdx.x * 256 + tid] = (tid < 128) ? chs[tid] : chq[tid - 128];
    // coalesced store ylds -> y0 (ws, bf16)
    {
        int o = tid >> 1, h = tid & 1;
#pragma unroll
        for (int jj = 0; jj < 4; ++jj) {
            int j = (h << 2) + jj;
            uint4 v = *(const uint4*)&ylds[(o << 6) + ((j ^ (o & 7)) << 3)];
            *(uint4*)(y0 + (size_t)(b * CO + o) * NN + n0 + (j << 3)) = v;
        }
    }
}

// ================= stat reduce + BN scale/shift: gpart -> sc[128], sh[128] =================
__global__ __launch_bounds__(256) void k_red_scale(
        const float* __restrict__ gpart, const float* __restrict__ g,
        const float* __restrict__ be, float* __restrict__ sc, float* __restrict__ sh) {
    __shared__ float wsum[4], wsq[4];
    int o = blockIdx.x, tid = threadIdx.x;     // 128 blocks, one per channel
    float s = 0.f, q = 0.f;
#pragma unroll
    for (int j = 0; j < 4; ++j) {
        int k = tid + (j << 8);
        s += gpart[k * 256 + o];
        q += gpart[k * 256 + 128 + o];
    }
#pragma unroll
    for (int d = 1; d < 64; d <<= 1) {
        s += __shfl_xor(s, d, 64);
        q += __shfl_xor(q, d, 64);
    }
    if ((tid & 63) == 0) { wsum[tid >> 6] = s; wsq[tid >> 6] = q; }
    __syncthreads();
    if (tid == 0) {
        float st = (wsum[0] + wsum[1]) + (wsum[2] + wsum[3]);
        float qt = (wsq[0] + wsq[1]) + (wsq[2] + wsq[3]);
        float mu = st * (1.f / NB);
        float var = qt * (1.f / NB) - mu * mu;
        float istd = 1.f / __fsqrt_rn(var + EPS);
        float scale = g[o] * istd;
        sc[o] = scale;
        sh[o] = be[o] - mu * scale;
    }
}

// ================= layer 1: BN0+ReLU -> MFMA gemm -> y1pre in place + stat partials =================
__global__ __launch_bounds__(256) void k_l1(
        u16* __restrict__ y, const float* __restrict__ sc0, const float* __restrict__ sh0,
        const u16* __restrict__ W1b, const float* __restrict__ b1,
        float* __restrict__ gpart) {
    __shared__ u16 xt[64 * CO];           // B-tile [n][k] swz (16KB)
    __shared__ u16 ylds[CO * 64];         // (16KB)
    __shared__ float chs[CO], chq[CO], sc[CO], sh[CO];
    int tid = threadIdx.x;
    int l = tid & 63, w = tid >> 6, ln = l & 15, q = l >> 4;
    int b = blockIdx.x >> 7, n0 = (blockIdx.x & 127) << 6;
    if (tid < 128) {
        sc[tid] = sc0[tid]; sh[tid] = sh0[tid];    // complete: dispatch boundary
        chs[tid] = 0.f; chq[tid] = 0.f;
    }
    __syncthreads();
    // stage y0 tile with BN0+ReLU via in-register transpose; 2 x 64 channels
#pragma unroll
    for (int it = 0; it < 2; ++it) {
        int c = (it << 6) + l;
        const u16* src = y + (size_t)(b * CO + c) * NN + n0 + (w << 4);
        uint4 r0 = *(const uint4*)src;
        uint4 r1 = *(const uint4*)(src + 8);
        u16 raw[16];
        *(uint4*)&raw[0] = r0;
        *(uint4*)&raw[8] = r1;
        float scale = sc[c], shift = sh[c];
        int cc = c >> 3, clo = c & 7;
#pragma unroll
        for (int i = 0; i < 16; ++i) {
            int n = (w << 4) + i;
            float hv = fmaxf(b2f(raw[i]) * scale + shift, 0.f);
            xt[(n << 7) + ((cc ^ (i & 7)) << 3) + clo] = f2b(hv);
        }
    }
    __syncthreads();
    f32x4 ac0[4], ac1[4];
#pragma unroll
    for (int nf = 0; nf < 4; ++nf) {
        ac0[nf] = f32x4{0.f, 0.f, 0.f, 0.f};
        ac1[nf] = f32x4{0.f, 0.f, 0.f, 0.f};
    }
    const u16* w1r0 = W1b + (32 * w + ln) * CO + 8 * q;
    const u16* w1r1 = w1r0 + 16 * CO;
#pragma unroll
    for (int s = 0; s < 4; ++s) {
        bf16x8 a0 = *(const bf16x8*)(w1r0 + 32 * s);
        bf16x8 a1 = *(const bf16x8*)(w1r1 + 32 * s);
#pragma unroll
        for (int nf = 0; nf < 4; ++nf) {
            bf16x8 bv = *(const bf16x8*)&xt[((16 * nf + ln) << 7) + (((4 * s + q) ^ (ln & 7)) << 3)];
            ac0[nf] = __builtin_amdgcn_mfma_f32_16x16x32_bf16(a0, bv, ac0[nf], 0, 0, 0);
            ac1[nf] = __builtin_amdgcn_mfma_f32_16x16x32_bf16(a1, bv, ac1[nf], 0, 0, 0);
        }
    }
    epilogue(ac0, ac1, b1, ylds, chs, chq, w, ln, q);
    __syncthreads();
    gpart[blockIdx.x * 256 + tid] = (tid < 128) ? chs[tid] : chq[tid - 128];
    // in-place store y1pre (bf16) over the same tile of ws
    {
        int o = tid >> 1, h = tid & 1;
#pragma unroll
        for (int jj = 0; jj < 4; ++jj) {
            int j = (h << 2) + jj;
            uint4 v = *(const uint4*)&ylds[(o << 6) + ((j ^ (o & 7)) << 3)];
            *(uint4*)(y + (size_t)(b * CO + o) * NN + n0 + (j << 3)) = v;
        }
    }
}

// ================= final BN1 + ReLU with inline per-channel stat reduce =================
__global__ __launch_bounds__(256) void k_bn1(
        const u16* __restrict__ y, const float* __restrict__ gpart,
        const float* __restrict__ g1, const float* __restrict__ be1,
        float* __restrict__ out) {
    __shared__ float wsum[4], wsq[4], bcast[2];
    int tid = threadIdx.x, bid = blockIdx.x;
    int o = (bid >> 2) & 127;
    float s = 0.f, q = 0.f;
#pragma unroll
    for (int j = 0; j < 4; ++j) {
        int k = tid + (j << 8);
        s += gpart[k * 256 + o];
        q += gpart[k * 256 + 128 + o];
    }
#pragma unroll
    for (int d = 1; d < 64; d <<= 1) {
        s += __shfl_xor(s, d, 64);
        q += __shfl_xor(q, d, 64);
    }
    if ((tid & 63) == 0) { wsum[tid >> 6] = s; wsq[tid >> 6] = q; }
    __syncthreads();
    if (tid == 0) {
        float st = (wsum[0] + wsum[1]) + (wsum[2] + wsum[3]);
        float qt = (wsq[0] + wsq[1]) + (wsq[2] + wsq[3]);
        float mu = st * (1.f / NB);
        float var = qt * (1.f / NB) - mu * mu;
        float istd = 1.f / __fsqrt_rn(var + EPS);
        float scale = g1[o] * istd;
        bcast[0] = scale;
        bcast[1] = be1[o] - mu * scale;
    }
    __syncthreads();
    float scale = bcast[0], shift = bcast[1];
    int t = bid * 256 + tid;
    size_t e0 = (size_t)t << 3;
    uint4 v = *(const uint4*)(y + e0);
    u16 raw[8];
    *(uint4*)raw = v;
    float r[8];
#pragma unroll
    for (int k = 0; k < 8; ++k)
        r[k] = fmaxf(b2f(raw[k]) * scale + shift, 0.f);
    *(float4*)(out + e0) = make_float4(r[0], r[1], r[2], r[3]);
    *(float4*)(out + e0 + 4) = make_float4(r[4], r[5], r[6], r[7]);
}

extern "C" void kernel_launch(void* const* d_in, const int* in_sizes, int n_in,
                              void* d_out, int out_size, void* d_ws, size_t ws_size,
                              hipStream_t stream) {
    const float* lt = (const float*)d_in[0];
    const float* lp = (const float*)d_in[1];
    const float* lf = (const float*)d_in[2];
    const float* ht = (const float*)d_in[3];
    const float* hp = (const float*)d_in[4];
    const float* hf = (const float*)d_in[5];
    const float* W0 = (const float*)d_in[6];
    const float* b0 = (const float*)d_in[7];
    const float* g0 = (const float*)d_in[8];
    const float* be0 = (const float*)d_in[9];
    const float* W1 = (const float*)d_in[10];
    const float* b1 = (const float*)d_in[11];
    const float* g1 = (const float*)d_in[12];
    const float* be1 = (const float*)d_in[13];

    char* ws = (char*)d_ws;
    u16* y0 = (u16*)ws;                         // 16.78 MB (y0, then y1pre in place)
    u16* hT = (u16*)(ws + 16777216);            // 4.19 MB
    int* idx = (int*)(ws + 20971520);           // 256 KB
    float* sc0 = (float*)(ws + 21233664);       // 512 B
    float* sh0 = (float*)(ws + 21234176);       // 512 B
    u16* W0b = (u16*)(ws + 21235712);           // 48 KB
    u16* W1b = (u16*)(ws + 21284864);           // 32 KB
    float* gpart = (float*)(ws + 21317632);     // 1 MB per-block stat partials (reused)

    k_pre<<<PRE_TOTAL, 256, 0, stream>>>(lt, lp, ht, hp, hf, W0, W1,
                                         idx, hT, W0b, W1b);
    k_l0<<<1024, 256, 0, stream>>>(lf, hT, idx, W0b, b0, y0, gpart);
    k_red_scale<<<128, 256, 0, stream>>>(gpart, g0, be0, sc0, sh0);
    k_l1<<<1024, 256, 0, stream>>>(y0, sc0, sh0, W1b, b1, gpart);
    k_bn1<<<4096, 256, 0, stream>>>(y0, gpart, g1, be1, (float*)d_out);
}

// Round 13
// 120.307 us; speedup vs baseline: 1.1781x; 1.1781x over previous
//
#include <hip/hip_runtime.h>
#include <hip/hip_bf16.h>
#include <hip/hip_cooperative_groups.h>

namespace cg = cooperative_groups;

#define BB 8
#define NN 8192
#define MM 2048
#define C1 64
#define C2 128
#define CIN 192
#define CO 128
#define NB (BB*NN)
#define EPS 1e-5f

typedef unsigned short u16;
typedef unsigned int u32;
typedef __bf16 bf16_t;
typedef bf16_t bf16x8 __attribute__((ext_vector_type(8)));
typedef float f32x4 __attribute__((ext_vector_type(4)));
typedef float f32x2 __attribute__((ext_vector_type(2)));

static __device__ __forceinline__ float b2f(u16 u) { return __uint_as_float(((u32)u) << 16); }
static __device__ __forceinline__ u16 f2b(float f) {
    __hip_bfloat16 h = __float2bfloat16(f);
    u16 u; __builtin_memcpy(&u, &h, 2); return u;
}
static __device__ __forceinline__ bf16x8 cvt8(float4 x, float4 y) {
    union { u16 u[8]; bf16x8 v; } cv;
    cv.u[0] = f2b(x.x); cv.u[1] = f2b(x.y); cv.u[2] = f2b(x.z); cv.u[3] = f2b(x.w);
    cv.u[4] = f2b(y.x); cv.u[5] = f2b(y.y); cv.u[6] = f2b(y.z); cv.u[7] = f2b(y.w);
    return cv.v;
}

// epilogue: bias add, per-channel sum/sumsq into LDS chs/chq, bf16 store to ylds (swz)
static __device__ __forceinline__ void epilogue(
        f32x4* ac0, f32x4* ac1, const float* bias, u16* yl,
        float* chs, float* chq, int w, int ln, int q) {
#pragma unroll
    for (int mf = 0; mf < 2; ++mf) {
        f32x4* A = mf ? ac1 : ac0;
        int chb = 32 * w + 16 * mf + 4 * q;
        float bs[4], ss[4] = {0.f, 0.f, 0.f, 0.f}, sq[4] = {0.f, 0.f, 0.f, 0.f};
#pragma unroll
        for (int r = 0; r < 4; ++r) bs[r] = bias[chb + r];
#pragma unroll
        for (int nf = 0; nf < 4; ++nf) {
            int n = (nf << 4) + ln;
#pragma unroll
            for (int r = 0; r < 4; ++r) {
                float y = A[nf][r] + bs[r];
                ss[r] += y; sq[r] += y * y;
                int o = chb + r;
                yl[(o << 6) + (n ^ ((o & 7) << 3))] = f2b(y);
            }
        }
#pragma unroll
        for (int r = 0; r < 4; ++r) {
            float v = ss[r], u2 = sq[r];
#pragma unroll
            for (int d = 1; d < 16; d <<= 1) {
                v += __shfl_xor(v, d, 64);
                u2 += __shfl_xor(u2, d, 64);
            }
            if (ln == 0) { atomicAdd(&chs[chb + r], v); atomicAdd(&chq[chb + r], u2); }
        }
    }
}

// =====================================================================
// Cooperative mega-kernel: argmin+transpose -> l0 -> red0 -> l1 -> red1 -> bn1
// grid 512 x 256, 2 blocks/CU. y0/y1 tiles live in LDS end-to-end.
// =====================================================================
struct KArgs {
    const float *lt, *lp, *ht, *hp, *hf, *lf;
    const float *W0, *b0, *g0, *be0, *W1, *b1, *g1, *be1;
    float* out;
    u16* hT;
    float *gpart, *sc0, *sh0, *sc1, *sh1;
};

__global__ __launch_bounds__(256, 2) void k_all(KArgs a) {
    __shared__ unsigned long long scratch8[3104];   // 24832 B scratch (hs / st / xt)
    __shared__ u16 ylds[2][CO * 64];                // 32 KB persistent y tiles
    __shared__ float chs[CO], chq[CO], scl[CO], shl[CO];
    __shared__ int idxs[128];
    __shared__ float wtmp[8];
    cg::grid_group grid = cg::this_grid();
    int bid = blockIdx.x, tid = threadIdx.x;
    int b = bid >> 6, blk = bid & 63;               // batch, tile-pair id (128 n per block)
    int l = tid & 63, w = tid >> 6, ln = l & 15, q = l >> 4;

    // ---------------- P0a: argmin for this block's own 128 queries ----------------
    {
        float* nx = (float*)scratch8;               // negated coords, SoA stride 260
        float* ny = nx + 8 * 260;
        for (int e = tid; e < MM; e += 256) {
            int p = e >> 8, i = e & 255;
            nx[p * 260 + i] = -a.ht[b * MM + e];
            ny[p * 260 + i] = -a.hp[b * MM + e];
        }
        __syncthreads();
        int qq = tid >> 3, p = tid & 7;             // 32 queries x 8 m-parts per round
        const float* nxp = &nx[p * 260];
        const float* nyp = &ny[p * 260];
        int mbase = p << 8;
        for (int r = 0; r < 4; ++r) {
            int n0 = blk * 128 + r * 32;
            float ltv = a.lt[b * NN + n0 + qq], lpv = a.lp[b * NN + n0 + qq];
            f32x2 lt2 = {ltv, ltv}, lp2 = {lpv, lpv};
            float dl[4] = {1e30f, 1e30f, 1e30f, 1e30f};
            float dpv[4] = {1e30f, 1e30f, 1e30f, 1e30f};
            int il[4] = {0, 0, 0, 0}, ipx[4] = {0, 0, 0, 0};
#pragma unroll 4
            for (int k = 0; k < 32; ++k) {
#pragma unroll
                for (int c = 0; c < 4; ++c) {
                    f32x2 xx = *(const f32x2*)&nxp[(k << 3) + (c << 1)];
                    f32x2 yy = *(const f32x2*)&nyp[(k << 3) + (c << 1)];
                    f32x2 dt, dp2, t2, u2, d2;
                    asm("v_pk_add_f32 %0, %1, %2" : "=v"(dt) : "v"(lt2), "v"(xx));
                    asm("v_pk_add_f32 %0, %1, %2" : "=v"(dp2) : "v"(lp2), "v"(yy));
                    asm("v_pk_mul_f32 %0, %1, %2" : "=v"(t2) : "v"(dt), "v"(dt));
                    asm("v_pk_mul_f32 %0, %1, %2" : "=v"(u2) : "v"(dp2), "v"(dp2));
                    asm("v_pk_add_f32 %0, %1, %2" : "=v"(d2) : "v"(t2), "v"(u2));
                    int i0 = (k << 3) + (c << 1);
                    bool h0 = d2[0] < dl[c];
                    dpv[c] = h0 ? dl[c] : dpv[c];
                    ipx[c] = h0 ? il[c] : ipx[c];
                    dl[c] = h0 ? d2[0] : dl[c];
                    il[c] = h0 ? i0 : il[c];
                    bool h1 = d2[1] < dl[c];
                    dpv[c] = h1 ? dl[c] : dpv[c];
                    ipx[c] = h1 ? il[c] : ipx[c];
                    dl[c] = h1 ? d2[1] : dl[c];
                    il[c] = h1 ? i0 + 1 : il[c];
                }
            }
            float bs = 1e30f; int bm = 0x7fffffff;
#pragma unroll
            for (int c = 0; c < 4; ++c) {
                float sl = __fsqrt_rn(dl[c]);
                float sp = __fsqrt_rn(dpv[c]);
                int cand = mbase + ((sp == sl) ? ipx[c] : il[c]);  // sqrt-tie -> earlier
                if (sl < bs || (sl == bs && cand < bm)) { bs = sl; bm = cand; }
            }
#pragma unroll
            for (int d = 1; d <= 4; d <<= 1) {
                float ov = __shfl_xor(bs, d, 64);
                int om = __shfl_xor(bm, d, 64);
                if (ov < bs || (ov == bs && om < bm)) { bs = ov; bm = om; }
            }
            if (p == 0) idxs[r * 32 + qq] = bm;     // stays in LDS: own n-range
        }
    }
    __syncthreads();
    // ---------------- P0b: one 64x64 hT transpose tile per block ----------------
    {
        u16 (*st)[65] = (u16(*)[65])scratch8;
        int m0 = (blk >> 1) * 64, c0 = (blk & 1) * 64;
        for (int e = tid; e < 4096; e += 256) {
            int i = e >> 6, j = e & 63;
            st[i][j] = f2b(a.hf[(b * C2 + c0 + i) * MM + m0 + j]);
        }
        __syncthreads();
        for (int e = tid; e < 4096; e += 256) {
            int ii = e & 63, jj = e >> 6;
            a.hT[(b * MM + m0 + jj) * C2 + c0 + ii] = st[ii][jj];
        }
    }
    grid.sync();

    // ---------------- P1: layer 0 on 2 tiles (y0 -> ylds, stats -> gpart) ----------------
    {
        u16* xt = (u16*)scratch8;                   // [64][CIN] swz, 24576 B
        if (tid < 128) { chs[tid] = 0.f; chq[tid] = 0.f; }
        for (int tl = 0; tl < 2; ++tl) {
            int n0 = blk * 128 + tl * 64;
            __syncthreads();
            {   // low_feats in-register transpose (lane = channel)
                const float* src = a.lf + (size_t)(b * C1 + l) * NN + n0 + (w << 4);
                float4 f0 = *(const float4*)src;
                float4 f1 = *(const float4*)(src + 4);
                float4 f2 = *(const float4*)(src + 8);
                float4 f3 = *(const float4*)(src + 12);
                float v[16] = {f0.x, f0.y, f0.z, f0.w, f1.x, f1.y, f1.z, f1.w,
                               f2.x, f2.y, f2.z, f2.w, f3.x, f3.y, f3.z, f3.w};
                int cc = l >> 3, clo = l & 7;
#pragma unroll
                for (int i = 0; i < 16; ++i) {
                    int n = (w << 4) + i;
                    xt[n * CIN + ((cc ^ (i & 7)) << 3) + clo] = f2b(v[i]);
                }
            }
            for (int e = tid; e < 1024; e += 256) { // gather (256B rows from hT)
                int n = e >> 4, c16 = e & 15;
                uint4 v = *(const uint4*)(a.hT + (size_t)(b * MM + idxs[tl * 64 + n]) * C2 + (c16 << 3));
                *(uint4*)&xt[n * CIN + (((8 + c16) ^ (n & 7)) << 3)] = v;
            }
            __syncthreads();
            f32x4 ac0[4], ac1[4];
#pragma unroll
            for (int nf = 0; nf < 4; ++nf) {
                ac0[nf] = f32x4{0.f, 0.f, 0.f, 0.f};
                ac1[nf] = f32x4{0.f, 0.f, 0.f, 0.f};
            }
            const float* w0r0 = a.W0 + (32 * w + ln) * CIN + 8 * q;
            const float* w0r1 = w0r0 + 16 * CIN;
#pragma unroll
            for (int s = 0; s < 6; ++s) {
                bf16x8 a0 = cvt8(*(const float4*)(w0r0 + 32 * s), *(const float4*)(w0r0 + 32 * s + 4));
                bf16x8 a1 = cvt8(*(const float4*)(w0r1 + 32 * s), *(const float4*)(w0r1 + 32 * s + 4));
#pragma unroll
                for (int nf = 0; nf < 4; ++nf) {
                    bf16x8 bv = *(const bf16x8*)&xt[(16 * nf + ln) * CIN + (((4 * s + q) ^ (ln & 7)) << 3)];
                    ac0[nf] = __builtin_amdgcn_mfma_f32_16x16x32_bf16(a0, bv, ac0[nf], 0, 0, 0);
                    ac1[nf] = __builtin_amdgcn_mfma_f32_16x16x32_bf16(a1, bv, ac1[nf], 0, 0, 0);
                }
            }
            epilogue(ac0, ac1, a.b0, ylds[tl], chs, chq, w, ln, q);
        }
        __syncthreads();
        a.gpart[bid * 256 + tid] = (tid < 128) ? chs[tid] : chq[tid - 128];
    }
    grid.sync();

    // ---------------- P2: reduce stats0 -> sc0/sh0 (blocks 0..127) ----------------
    if (bid < 128) {
        int o = bid;
        float s = a.gpart[tid * 256 + o] + a.gpart[(tid + 256) * 256 + o];
        float qv = a.gpart[tid * 256 + 128 + o] + a.gpart[(tid + 256) * 256 + 128 + o];
#pragma unroll
        for (int d = 1; d < 64; d <<= 1) {
            s += __shfl_xor(s, d, 64);
            qv += __shfl_xor(qv, d, 64);
        }
        if ((tid & 63) == 0) { wtmp[tid >> 6] = s; wtmp[4 + (tid >> 6)] = qv; }
        __syncthreads();
        if (tid == 0) {
            float st = (wtmp[0] + wtmp[1]) + (wtmp[2] + wtmp[3]);
            float qt = (wtmp[4] + wtmp[5]) + (wtmp[6] + wtmp[7]);
            float mu = st * (1.f / NB);
            float var = qt * (1.f / NB) - mu * mu;
            float istd = 1.f / __fsqrt_rn(var + EPS);
            float scale = a.g0[o] * istd;
            a.sc0[o] = scale;
            a.sh0[o] = a.be0[o] - mu * scale;
        }
    }
    grid.sync();

    // ---------------- P3: layer 1 (ylds -> bn0+relu -> gemm -> ylds, stats) ----------------
    {
        u16* xt = (u16*)scratch8;                   // [64][128] swz, 16384 B
        if (tid < 128) {
            scl[tid] = a.sc0[tid]; shl[tid] = a.sh0[tid];
            chs[tid] = 0.f; chq[tid] = 0.f;
        }
        for (int tl = 0; tl < 2; ++tl) {
            __syncthreads();
#pragma unroll
            for (int it = 0; it < 2; ++it) {        // restage from LDS ylds
                int c = (it << 6) + l;
                int s5 = c & 7;
                uint4 r0 = *(const uint4*)&ylds[tl][(c << 6) + ((((w << 1)) ^ s5) << 3)];
                uint4 r1 = *(const uint4*)&ylds[tl][(c << 6) + ((((w << 1) + 1) ^ s5) << 3)];
                u16 raw[16];
                *(uint4*)&raw[0] = r0;
                *(uint4*)&raw[8] = r1;
                float scale = scl[c], shift = shl[c];
                int cc = c >> 3, clo = c & 7;
#pragma unroll
                for (int i = 0; i < 16; ++i) {
                    int n = (w << 4) + i;
                    float hv = fmaxf(b2f(raw[i]) * scale + shift, 0.f);
                    xt[(n << 7) + ((cc ^ (i & 7)) << 3) + clo] = f2b(hv);
                }
            }
            __syncthreads();
            f32x4 ac0[4], ac1[4];
#pragma unroll
            for (int nf = 0; nf < 4; ++nf) {
                ac0[nf] = f32x4{0.f, 0.f, 0.f, 0.f};
                ac1[nf] = f32x4{0.f, 0.f, 0.f, 0.f};
            }
            const float* w1r0 = a.W1 + (32 * w + ln) * CO + 8 * q;
            const float* w1r1 = w1r0 + 16 * CO;
#pragma unroll
            for (int s = 0; s < 4; ++s) {
                bf16x8 a0 = cvt8(*(const float4*)(w1r0 + 32 * s), *(const float4*)(w1r0 + 32 * s + 4));
                bf16x8 a1 = cvt8(*(const float4*)(w1r1 + 32 * s), *(const float4*)(w1r1 + 32 * s + 4));
#pragma unroll
                for (int nf = 0; nf < 4; ++nf) {
                    bf16x8 bv = *(const bf16x8*)&xt[((16 * nf + ln) << 7) + (((4 * s + q) ^ (ln & 7)) << 3)];
                    ac0[nf] = __builtin_amdgcn_mfma_f32_16x16x32_bf16(a0, bv, ac0[nf], 0, 0, 0);
                    ac1[nf] = __builtin_amdgcn_mfma_f32_16x16x32_bf16(a1, bv, ac1[nf], 0, 0, 0);
                }
            }
            epilogue(ac0, ac1, a.b1, ylds[tl], chs, chq, w, ln, q);
        }
        __syncthreads();
        a.gpart[bid * 256 + tid] = (tid < 128) ? chs[tid] : chq[tid - 128];
    }
    grid.sync();

    // ---------------- P4: reduce stats1 -> sc1/sh1 ----------------
    if (bid < 128) {
        int o = bid;
        float s = a.gpart[tid * 256 + o] + a.gpart[(tid + 256) * 256 + o];
        float qv = a.gpart[tid * 256 + 128 + o] + a.gpart[(tid + 256) * 256 + 128 + o];
#pragma unroll
        for (int d = 1; d < 64; d <<= 1) {
            s += __shfl_xor(s, d, 64);
            qv += __shfl_xor(qv, d, 64);
        }
        if ((tid & 63) == 0) { wtmp[tid >> 6] = s; wtmp[4 + (tid >> 6)] = qv; }
        __syncthreads();
        if (tid == 0) {
            float st = (wtmp[0] + wtmp[1]) + (wtmp[2] + wtmp[3]);
            float qt = (wtmp[4] + wtmp[5]) + (wtmp[6] + wtmp[7]);
            float mu = st * (1.f / NB);
            float var = qt * (1.f / NB) - mu * mu;
            float istd = 1.f / __fsqrt_rn(var + EPS);
            float scale = a.g1[o] * istd;
            a.sc1[o] = scale;
            a.sh1[o] = a.be1[o] - mu * scale;
        }
    }
    grid.sync();

    // ---------------- P5: BN1 + ReLU from ylds -> f32 out ----------------
    if (tid < 128) { scl[tid] = a.sc1[tid]; shl[tid] = a.sh1[tid]; }
    __syncthreads();
    {
        int o = tid >> 1, h = tid & 1;
        float scale = scl[o], shift = shl[o];
#pragma unroll
        for (int tl = 0; tl < 2; ++tl) {
            int n0 = blk * 128 + tl * 64;
#pragma unroll
            for (int jj = 0; jj < 4; ++jj) {
                int j = (h << 2) + jj;
                uint4 v = *(const uint4*)&ylds[tl][(o << 6) + ((j ^ (o & 7)) << 3)];
                u16 raw[8];
                *(uint4*)raw = v;
                float r[8];
#pragma unroll
                for (int k = 0; k < 8; ++k)
                    r[k] = fmaxf(b2f(raw[k]) * scale + shift, 0.f);
                float* dst = a.out + (size_t)(b * CO + o) * NN + n0 + (j << 3);
                *(float4*)dst = make_float4(r[0], r[1], r[2], r[3]);
                *(float4*)(dst + 4) = make_float4(r[4], r[5], r[6], r[7]);
            }
        }
    }
}

// =====================================================================
// Fallback path: round-11 verified 5-dispatch pipeline (120.3 us)
// =====================================================================
#define PRE_ARGMIN 2048
#define PRE_PREPH  (PRE_ARGMIN + 512)
#define PRE_TOTAL  (PRE_PREPH + 96)

__global__ __launch_bounds__(256) void k_pre(
        const float* __restrict__ lt_, const float* __restrict__ lp_,
        const float* __restrict__ ht_, const float* __restrict__ hp_,
        const float* __restrict__ hf, const float* __restrict__ W0, const float* __restrict__ W1,
        int* __restrict__ idx, u16* __restrict__ hT,
        u16* __restrict__ W0b, u16* __restrict__ W1b) {
    __shared__ float smem[2 * 8 * 260];
    int bid = blockIdx.x, tid = threadIdx.x;
    if (bid < PRE_ARGMIN) {
        int b = bid >> 8;
        int n0 = (bid & 255) << 5;
        float* nx = smem;
        float* ny = smem + 8 * 260;
        for (int e = tid; e < MM; e += 256) {
            int p = e >> 8, i = e & 255;
            nx[p * 260 + i] = -ht_[b * MM + e];
            ny[p * 260 + i] = -hp_[b * MM + e];
        }
        __syncthreads();
        int qq = tid >> 3, p = tid & 7;
        float ltv = lt_[b * NN + n0 + qq];
        float lpv = lp_[b * NN + n0 + qq];
        f32x2 lt2 = {ltv, ltv}, lp2 = {lpv, lpv};
        float dl[4] = {1e30f, 1e30f, 1e30f, 1e30f};
        float dpv[4] = {1e30f, 1e30f, 1e30f, 1e30f};
        int il[4] = {0, 0, 0, 0}, ipx[4] = {0, 0, 0, 0};
        const float* nxp = &nx[p * 260];
        const float* nyp = &ny[p * 260];
#pragma unroll 4
        for (int k = 0; k < 32; ++k) {
#pragma unroll
            for (int c = 0; c < 4; ++c) {
                f32x2 xx = *(const f32x2*)&nxp[(k << 3) + (c << 1)];
                f32x2 yy = *(const f32x2*)&nyp[(k << 3) + (c << 1)];
                f32x2 dt, dp2, t2, u2, d2;
                asm("v_pk_add_f32 %0, %1, %2" : "=v"(dt) : "v"(lt2), "v"(xx));
                asm("v_pk_add_f32 %0, %1, %2" : "=v"(dp2) : "v"(lp2), "v"(yy));
                asm("v_pk_mul_f32 %0, %1, %2" : "=v"(t2) : "v"(dt), "v"(dt));
                asm("v_pk_mul_f32 %0, %1, %2" : "=v"(u2) : "v"(dp2), "v"(dp2));
                asm("v_pk_add_f32 %0, %1, %2" : "=v"(d2) : "v"(t2), "v"(u2));
                int i0 = (k << 3) + (c << 1);
                bool h0 = d2[0] < dl[c];
                dpv[c] = h0 ? dl[c] : dpv[c];
                ipx[c] = h0 ? il[c] : ipx[c];
                dl[c] = h0 ? d2[0] : dl[c];
                il[c] = h0 ? i0 : il[c];
                bool h1 = d2[1] < dl[c];
                dpv[c] = h1 ? dl[c] : dpv[c];
                ipx[c] = h1 ? il[c] : ipx[c];
                dl[c] = h1 ? d2[1] : dl[c];
                il[c] = h1 ? i0 + 1 : il[c];
            }
        }
        int mbase = p << 8;
        float bs = 1e30f; int bm = 0x7fffffff;
#pragma unroll
        for (int c = 0; c < 4; ++c) {
            float sl = __fsqrt_rn(dl[c]);
            float sp = __fsqrt_rn(dpv[c]);
            int cand = mbase + ((sp == sl) ? ipx[c] : il[c]);
            if (sl < bs || (sl == bs && cand < bm)) { bs = sl; bm = cand; }
        }
#pragma unroll
        for (int d = 1; d <= 4; d <<= 1) {
            float ov = __shfl_xor(bs, d, 64);
            int om = __shfl_xor(bm, d, 64);
            if (ov < bs || (ov == bs && om < bm)) { bs = ov; bm = om; }
        }
        if (p == 0) idx[b * NN + n0 + qq] = bm;
    } else if (bid < PRE_PREPH) {
        u16 (*s)[65] = (u16(*)[65])smem;
        int bid2 = bid - PRE_ARGMIN;
        int b = bid2 >> 6, m0 = ((bid2 >> 1) & 31) * 64, c0 = (bid2 & 1) * 64;
        for (int e = tid; e < 64 * 64; e += 256) {
            int i = e >> 6, j = e & 63;
            s[i][j] = f2b(hf[(b * C2 + c0 + i) * MM + m0 + j]);
        }
        __syncthreads();
        for (int e = tid; e < 64 * 64; e += 256) {
            int ii = e & 63, jj = e >> 6;
            hT[(b * MM + m0 + jj) * C2 + c0 + ii] = s[ii][jj];
        }
    } else {
        int t = (bid - PRE_PREPH) * 256 + tid;
        if (t < CIN * CO) W0b[t] = f2b(W0[t]);
        if (t < CO * CO)  W1b[t] = f2b(W1[t]);
    }
}

__global__ __launch_bounds__(256) void k_l0(
        const float* __restrict__ lf, const u16* __restrict__ hT, const int* __restrict__ idx,
        const u16* __restrict__ W0b, const float* __restrict__ b0,
        u16* __restrict__ y0, float* __restrict__ gpart) {
    __shared__ u16 xt[64 * CIN];
    __shared__ u16 yl[CO * 64];
    __shared__ float chs[CO], chq[CO];
    __shared__ int idxs[64];
    int tid = threadIdx.x;
    int l = tid & 63, w = tid >> 6, ln = l & 15, q = l >> 4;
    int b = blockIdx.x >> 7, n0 = (blockIdx.x & 127) << 6;
    if (tid < 64) idxs[tid] = idx[b * NN + n0 + tid];
    if (tid < 128) { chs[tid] = 0.f; chq[tid] = 0.f; }
    __syncthreads();
    {
        const float* src = lf + (size_t)(b * C1 + l) * NN + n0 + (w << 4);
        float4 f0 = *(const float4*)src;
        float4 f1 = *(const float4*)(src + 4);
        float4 f2 = *(const float4*)(src + 8);
        float4 f3 = *(const float4*)(src + 12);
        float v[16] = {f0.x, f0.y, f0.z, f0.w, f1.x, f1.y, f1.z, f1.w,
                       f2.x, f2.y, f2.z, f2.w, f3.x, f3.y, f3.z, f3.w};
        int cc = l >> 3, clo = l & 7;
#pragma unroll
        for (int i = 0; i < 16; ++i) {
            int n = (w << 4) + i;
            xt[n * CIN + ((cc ^ (i & 7)) << 3) + clo] = f2b(v[i]);
        }
    }
    for (int e = tid; e < 1024; e += 256) {
        int n = e >> 4, c16 = e & 15;
        uint4 v = *(const uint4*)(hT + (size_t)(b * MM + idxs[n]) * C2 + (c16 << 3));
        *(uint4*)&xt[n * CIN + (((8 + c16) ^ (n & 7)) << 3)] = v;
    }
    __syncthreads();
    f32x4 ac0[4], ac1[4];
#pragma unroll
    for (int nf = 0; nf < 4; ++nf) {
        ac0[nf] = f32x4{0.f, 0.f, 0.f, 0.f};
        ac1[nf] = f32x4{0.f, 0.f, 0.f, 0.f};
    }
    const u16* w0r0 = W0b + (32 * w + ln) * CIN + 8 * q;
    const u16* w0r1 = w0r0 + 16 * CIN;
#pragma unroll
    for (int s = 0; s < 6; ++s) {
        bf16x8 a0 = *(const bf16x8*)(w0r0 + 32 * s);
        bf16x8 a1 = *(const bf16x8*)(w0r1 + 32 * s);
#pragma unroll
        for (int nf = 0; nf < 4; ++nf) {
            bf16x8 bv = *(const bf16x8*)&xt[(16 * nf + ln) * CIN + (((4 * s + q) ^ (ln & 7)) << 3)];
            ac0[nf] = __builtin_amdgcn_mfma_f32_16x16x32_bf16(a0, bv, ac0[nf], 0, 0, 0);
            ac1[nf] = __builtin_amdgcn_mfma_f32_16x16x32_bf16(a1, bv, ac1[nf], 0, 0, 0);
        }
    }
    epilogue(ac0, ac1, b0, yl, chs, chq, w, ln, q);
    __syncthreads();
    gpart[blockIdx.x * 256 + tid] = (tid < 128) ? chs[tid] : chq[tid - 128];
    {
        int o = tid >> 1, h = tid & 1;
#pragma unroll
        for (int jj = 0; jj < 4; ++jj) {
            int j = (h << 2) + jj;
            uint4 v = *(const uint4*)&yl[(o << 6) + ((j ^ (o & 7)) << 3)];
            *(uint4*)(y0 + (size_t)(b * CO + o) * NN + n0 + (j << 3)) = v;
        }
    }
}

__global__ __launch_bounds__(256) void k_red_scale(
        const float* __restrict__ gpart, const float* __restrict__ g,
        const float* __restrict__ be, float* __restrict__ sc, float* __restrict__ sh) {
    __shared__ float wsum[4], wsq[4];
    int o = blockIdx.x, tid = threadIdx.x;
    float s = 0.f, q = 0.f;
#pragma unroll
    for (int j = 0; j < 4; ++j) {
        int k = tid + (j << 8);
        s += gpart[k * 256 + o];
        q += gpart[k * 256 + 128 + o];
    }
#pragma unroll
    for (int d = 1; d < 64; d <<= 1) {
        s += __shfl_xor(s, d, 64);
        q += __shfl_xor(q, d, 64);
    }
    if ((tid & 63) == 0) { wsum[tid >> 6] = s; wsq[tid >> 6] = q; }
    __syncthreads();
    if (tid == 0) {
        float st = (wsum[0] + wsum[1]) + (wsum[2] + wsum[3]);
        float qt = (wsq[0] + wsq[1]) + (wsq[2] + wsq[3]);
        float mu = st * (1.f / NB);
        float var = qt * (1.f / NB) - mu * mu;
        float istd = 1.f / __fsqrt_rn(var + EPS);
        float scale = g[o] * istd;
        sc[o] = scale;
        sh[o] = be[o] - mu * scale;
    }
}

__global__ __launch_bounds__(256) void k_l1(
        u16* __restrict__ y, const float* __restrict__ sc0, const float* __restrict__ sh0,
        const u16* __restrict__ W1b, const float* __restrict__ b1,
        float* __restrict__ gpart) {
    __shared__ u16 xt[64 * CO];
    __shared__ u16 yl[CO * 64];
    __shared__ float chs[CO], chq[CO], sc[CO], sh[CO];
    int tid = threadIdx.x;
    int l = tid & 63, w = tid >> 6, ln = l & 15, q = l >> 4;
    int b = blockIdx.x >> 7, n0 = (blockIdx.x & 127) << 6;
    if (tid < 128) {
        sc[tid] = sc0[tid]; sh[tid] = sh0[tid];
        chs[tid] = 0.f; chq[tid] = 0.f;
    }
    __syncthreads();
#pragma unroll
    for (int it = 0; it < 2; ++it) {
        int c = (it << 6) + l;
        const u16* src = y + (size_t)(b * CO + c) * NN + n0 + (w << 4);
        uint4 r0 = *(const uint4*)src;
        uint4 r1 = *(const uint4*)(src + 8);
        u16 raw[16];
        *(uint4*)&raw[0] = r0;
        *(uint4*)&raw[8] = r1;
        float scale = sc[c], shift = sh[c];
        int cc = c >> 3, clo = c & 7;
#pragma unroll
        for (int i = 0; i < 16; ++i) {
            int n = (w << 4) + i;
            float hv = fmaxf(b2f(raw[i]) * scale + shift, 0.f);
            xt[(n << 7) + ((cc ^ (i & 7)) << 3) + clo] = f2b(hv);
        }
    }
    __syncthreads();
    f32x4 ac0[4], ac1[4];
#pragma unroll
    for (int nf = 0; nf < 4; ++nf) {
        ac0[nf] = f32x4{0.f, 0.f, 0.f, 0.f};
        ac1[nf] = f32x4{0.f, 0.f, 0.f, 0.f};
    }
    const u16* w1r0 = W1b + (32 * w + ln) * CO + 8 * q;
    const u16* w1r1 = w1r0 + 16 * CO;
#pragma unroll
    for (int s = 0; s < 4; ++s) {
        bf16x8 a0 = *(const bf16x8*)(w1r0 + 32 * s);
        bf16x8 a1 = *(const bf16x8*)(w1r1 + 32 * s);
#pragma unroll
        for (int nf = 0; nf < 4; ++nf) {
            bf16x8 bv = *(const bf16x8*)&xt[((16 * nf + ln) << 7) + (((4 * s + q) ^ (ln & 7)) << 3)];
            ac0[nf] = __builtin_amdgcn_mfma_f32_16x16x32_bf16(a0, bv, ac0[nf], 0, 0, 0);
            ac1[nf] = __builtin_amdgcn_mfma_f32_16x16x32_bf16(a1, bv, ac1[nf], 0, 0, 0);
        }
    }
    epilogue(ac0, ac1, b1, yl, chs, chq, w, ln, q);
    __syncthreads();
    gpart[blockIdx.x * 256 + tid] = (tid < 128) ? chs[tid] : chq[tid - 128];
    {
        int o = tid >> 1, h = tid & 1;
#pragma unroll
        for (int jj = 0; jj < 4; ++jj) {
            int j = (h << 2) + jj;
            uint4 v = *(const uint4*)&yl[(o << 6) + ((j ^ (o & 7)) << 3)];
            *(uint4*)(y + (size_t)(b * CO + o) * NN + n0 + (j << 3)) = v;
        }
    }
}

__global__ __launch_bounds__(256) void k_bn1(
        const u16* __restrict__ y, const float* __restrict__ gpart,
        const float* __restrict__ g1, const float* __restrict__ be1,
        float* __restrict__ out) {
    __shared__ float wsum[4], wsq[4], bcast[2];
    int tid = threadIdx.x, bid = blockIdx.x;
    int o = (bid >> 2) & 127;
    float s = 0.f, q = 0.f;
#pragma unroll
    for (int j = 0; j < 4; ++j) {
        int k = tid + (j << 8);
        s += gpart[k * 256 + o];
        q += gpart[k * 256 + 128 + o];
    }
#pragma unroll
    for (int d = 1; d < 64; d <<= 1) {
        s += __shfl_xor(s, d, 64);
        q += __shfl_xor(q, d, 64);
    }
    if ((tid & 63) == 0) { wsum[tid >> 6] = s; wsq[tid >> 6] = q; }
    __syncthreads();
    if (tid == 0) {
        float st = (wsum[0] + wsum[1]) + (wsum[2] + wsum[3]);
        float qt = (wsq[0] + wsq[1]) + (wsq[2] + wsq[3]);
        float mu = st * (1.f / NB);
        float var = qt * (1.f / NB) - mu * mu;
        float istd = 1.f / __fsqrt_rn(var + EPS);
        float scale = g1[o] * istd;
        bcast[0] = scale;
        bcast[1] = be1[o] - mu * scale;
    }
    __syncthreads();
    float scale = bcast[0], shift = bcast[1];
    int t = bid * 256 + tid;
    size_t e0 = (size_t)t << 3;
    uint4 v = *(const uint4*)(y + e0);
    u16 raw[8];
    *(uint4*)raw = v;
    float r[8];
#pragma unroll
    for (int k = 0; k < 8; ++k)
        r[k] = fmaxf(b2f(raw[k]) * scale + shift, 0.f);
    *(float4*)(out + e0) = make_float4(r[0], r[1], r[2], r[3]);
    *(float4*)(out + e0 + 4) = make_float4(r[4], r[5], r[6], r[7]);
}

extern "C" void kernel_launch(void* const* d_in, const int* in_sizes, int n_in,
                              void* d_out, int out_size, void* d_ws, size_t ws_size,
                              hipStream_t stream) {
    const float* lt = (const float*)d_in[0];
    const float* lp = (const float*)d_in[1];
    const float* lf = (const float*)d_in[2];
    const float* ht = (const float*)d_in[3];
    const float* hp = (const float*)d_in[4];
    const float* hf = (const float*)d_in[5];
    const float* W0 = (const float*)d_in[6];
    const float* b0 = (const float*)d_in[7];
    const float* g0 = (const float*)d_in[8];
    const float* be0 = (const float*)d_in[9];
    const float* W1 = (const float*)d_in[10];
    const float* b1 = (const float*)d_in[11];
    const float* g1 = (const float*)d_in[12];
    const float* be1 = (const float*)d_in[13];
    char* ws = (char*)d_ws;

    // ---- cooperative path (preferred) ----
    int maxb = 0;
    hipError_t oerr = hipOccupancyMaxActiveBlocksPerMultiprocessor(&maxb, k_all, 256, 0);
    if (oerr == hipSuccess && maxb >= 2) {
        u16* hT = (u16*)ws;                         // 4.19 MB
        float* gpart = (float*)(ws + 4194304);      // 512 KB
        float* sc0 = (float*)(ws + 4718592);
        float* sh0 = sc0 + 128;
        float* sc1 = sh0 + 128;
        float* sh1 = sc1 + 128;
        KArgs args = {lt, lp, ht, hp, hf, lf, W0, b0, g0, be0, W1, b1, g1, be1,
                      (float*)d_out, hT, gpart, sc0, sh0, sc1, sh1};
        void* kp[] = {&args};
        hipError_t lerr = hipLaunchCooperativeKernel(k_all, dim3(512), dim3(256), kp, 0, stream);
        if (lerr == hipSuccess) return;
    }

    // ---- fallback: round-11 verified 5-dispatch pipeline ----
    u16* y0 = (u16*)ws;                             // 16.78 MB
    u16* hT = (u16*)(ws + 16777216);                // 4.19 MB
    int* idx = (int*)(ws + 20971520);               // 256 KB
    float* sc0 = (float*)(ws + 21233664);
    float* sh0 = (float*)(ws + 21234176);
    u16* W0b = (u16*)(ws + 21235712);
    u16* W1b = (u16*)(ws + 21284864);
    float* gpart = (float*)(ws + 21317632);
    k_pre<<<PRE_TOTAL, 256, 0, stream>>>(lt, lp, ht, hp, hf, W0, W1, idx, hT, W0b, W1b);
    k_l0<<<1024, 256, 0, stream>>>(lf, hT, idx, W0b, b0, y0, gpart);
    k_red_scale<<<128, 256, 0, stream>>>(gpart, g0, be0, sc0, sh0);
    k_l1<<<1024, 256, 0, stream>>>(y0, sc0, sh0, W1b, b1, gpart);
    k_bn1<<<4096, 256, 0, stream>>>(y0, gpart, g1, be1, (float*)d_out);
}

// Round 14
// 107.698 us; speedup vs baseline: 1.3160x; 1.1171x over previous
//
#include <hip/hip_runtime.h>
#include <hip/hip_bf16.h>

#define BB 8
#define NN 8192
#define MM 2048
#define C1 64
#define C2 128
#define CIN 192
#define CO 128
#define NB (BB*NN)
#define EPS 1e-5f

typedef unsigned short u16;
typedef unsigned int u32;
typedef __bf16 bf16_t;
typedef bf16_t bf16x8 __attribute__((ext_vector_type(8)));
typedef float f32x4 __attribute__((ext_vector_type(4)));

static __device__ __forceinline__ float b2f(u16 u) { return __uint_as_float(((u32)u) << 16); }
static __device__ __forceinline__ u16 f2b(float f) {
    __hip_bfloat16 h = __float2bfloat16(f);
    u16 u; __builtin_memcpy(&u, &h, 2); return u;
}

// ---------------- weights f32 -> bf16 (same layout) ----------------
__global__ void k_prep_w(const float* __restrict__ W0, const float* __restrict__ W1,
                         u16* __restrict__ W0b, u16* __restrict__ W1b) {
    int t = blockIdx.x * 256 + threadIdx.x;
    if (t < CIN * CO) W0b[t] = f2b(W0[t]);
    if (t < CO * CO)  W1b[t] = f2b(W1[t]);
}

// ---------------- high_feats transpose: f32 [B][C2][M] -> bf16 [B][M][C2] ----------------
__global__ void k_prep_h(const float* __restrict__ hf, u16* __restrict__ hT) {
    __shared__ u16 s[64][65];
    int b = blockIdx.x, m0 = blockIdx.y * 64, c0 = blockIdx.z * 64;
    for (int e = threadIdx.x; e < 64 * 64; e += 256) {
        int i = e >> 6, j = e & 63;                 // i: c, j: m (coalesced in m)
        s[i][j] = f2b(hf[(b * C2 + c0 + i) * MM + m0 + j]);
    }
    __syncthreads();
    for (int e = threadIdx.x; e < 64 * 64; e += 256) {
        int ii = e & 63, jj = e >> 6;               // coalesced in c
        hT[(b * MM + m0 + jj) * C2 + c0 + ii] = s[ii][jj];
    }
}

// ---------------- nearest neighbor: branchless exact scan, b128 LDS reads ----------------
// d2 via rn mul,mul,add (no FMA) == np. Per chain keep LAST hit (strictly-decreasing d2)
// AND PREVIOUS hit; sqrt-tie promotes prev (earlier index) -- matches np.argmin over
// sqrt with first-index ties. ds_read_b128 delivers 2 candidates -> half the DS-pipe
// load vs b64/candidate (round-12 analysis: argmin was LDS-pipe-bound).
__global__ __launch_bounds__(256) void k_argmin(
        const float* __restrict__ lt_, const float* __restrict__ lp_,
        const float* __restrict__ ht_, const float* __restrict__ hp_,
        int* __restrict__ idx) {
    __shared__ float2 hs[8 * 260];                  // stride 260: 2-way bank alias (free)
    int b = blockIdx.x >> 8;                        // 256 blocks per batch
    int n0 = (blockIdx.x & 255) << 5;               // 32 queries per block
    int tid = threadIdx.x;
    for (int e = tid; e < MM; e += 256) {
        int p = e >> 8, i = e & 255;
        hs[p * 260 + i] = make_float2(ht_[b * MM + e], hp_[b * MM + e]);
    }
    __syncthreads();
    int q = tid >> 3, p = tid & 7;                  // 32 queries x 8 m-parts per block
    float lt = lt_[b * NN + n0 + q];
    float lp = lp_[b * NN + n0 + q];
    float dl[4] = {1e30f, 1e30f, 1e30f, 1e30f};
    float dpv[4] = {1e30f, 1e30f, 1e30f, 1e30f};
    int il[4] = {0, 0, 0, 0}, ipx[4] = {0, 0, 0, 0};   // local indices 0..255
    const float2* hp2 = &hs[p * 260];
#pragma unroll 8
    for (int k = 0; k < 64; ++k) {                  // 4 cands/iter via 2x ds_read_b128
        f32x4 v0 = *(const f32x4*)&hp2[k * 4];      // cands 4k, 4k+1 (x,y,x,y)
        f32x4 v1 = *(const f32x4*)&hp2[k * 4 + 2];  // cands 4k+2, 4k+3
        float xs[4] = {v0[0], v0[2], v1[0], v1[2]};
        float ys[4] = {v0[1], v0[3], v1[1], v1[3]};
#pragma unroll
        for (int c = 0; c < 4; ++c) {               // chain c: cands 4k+c (ascending)
            float dt = lt - xs[c];
            float dp = lp - ys[c];
            float d2 = __fadd_rn(__fmul_rn(dt, dt), __fmul_rn(dp, dp)); // no-FMA = np
            bool hit = d2 < dl[c];                  // strict <
            dpv[c] = hit ? dl[c] : dpv[c];
            ipx[c] = hit ? il[c] : ipx[c];
            dl[c]  = hit ? d2 : dl[c];
            il[c]  = hit ? (k * 4 + c) : il[c];
        }
    }
    int mbase = p << 8;
    float bs = 1e30f; int bm = 0x7fffffff;
#pragma unroll
    for (int c = 0; c < 4; ++c) {
        float sl = __fsqrt_rn(dl[c]);
        float sp = __fsqrt_rn(dpv[c]);
        int cand = mbase + ((sp == sl) ? ipx[c] : il[c]);  // sqrt-tie -> earlier hit
        if (sl < bs || (sl == bs && cand < bm)) { bs = sl; bm = cand; }
    }
#pragma unroll
    for (int d = 1; d <= 4; d <<= 1) {              // merge 8 parts (lanes 8q+p)
        float ov = __shfl_xor(bs, d, 64);
        int om = __shfl_xor(bm, d, 64);
        if (ov < bs || (ov == bs && om < bm)) { bs = ov; bm = om; }
    }
    if (p == 0) idx[b * NN + n0 + q] = bm;
}

// epilogue: bias add, per-channel sum/sumsq into LDS chs/chq, bf16 store to ylds
static __device__ __forceinline__ void epilogue(
        f32x4* ac0, f32x4* ac1, const float* bias, u16* yl,
        float* chs, float* chq, int w, int ln, int q) {
#pragma unroll
    for (int mf = 0; mf < 2; ++mf) {
        f32x4* A = mf ? ac1 : ac0;
        int chb = 32 * w + 16 * mf + 4 * q;
        float bs[4], ss[4] = {0.f, 0.f, 0.f, 0.f}, sq[4] = {0.f, 0.f, 0.f, 0.f};
#pragma unroll
        for (int r = 0; r < 4; ++r) bs[r] = bias[chb + r];
#pragma unroll
        for (int nf = 0; nf < 4; ++nf) {
            int n = (nf << 4) + ln;
#pragma unroll
            for (int r = 0; r < 4; ++r) {
                float y = A[nf][r] + bs[r];
                ss[r] += y; sq[r] += y * y;
                int o = chb + r;
                yl[(o << 6) + (n ^ ((o & 7) << 3))] = f2b(y);
            }
        }
#pragma unroll
        for (int r = 0; r < 4; ++r) {
            float v = ss[r], u2 = sq[r];
#pragma unroll
            for (int d = 1; d < 16; d <<= 1) {
                v += __shfl_xor(v, d, 64);
                u2 += __shfl_xor(u2, d, 64);
            }
            if (ln == 0) { atomicAdd(&chs[chb + r], v); atomicAdd(&chq[chb + r], u2); }
        }
    }
}

// ---------------- deterministic stat reduce: gpart[1024][256] -> gout[256] ----------------
__global__ __launch_bounds__(256) void k_red(const float* __restrict__ gpart,
                                             float* __restrict__ gout) {
    __shared__ float part[4];
    int c = blockIdx.x;                    // one block per channel-slot (256)
    int t = threadIdx.x;
    float s = 0.f;
#pragma unroll
    for (int k = 0; k < 4; ++k)
        s += gpart[(t + (k << 8)) * 256 + c];
#pragma unroll
    for (int d = 1; d < 64; d <<= 1)
        s += __shfl_xor(s, d, 64);
    if ((t & 63) == 0) part[t >> 6] = s;
    __syncthreads();
    if (t == 0) gout[c] = (part[0] + part[1]) + (part[2] + part[3]);
}

// ---------------- layer 0: gather + MFMA gemm + bias -> y0 (ws, bf16) + stat partials ----------------
__global__ __launch_bounds__(256) void k_l0(
        const float* __restrict__ lf, const u16* __restrict__ hT, const int* __restrict__ idx,
        const u16* __restrict__ W0b, const float* __restrict__ b0,
        u16* __restrict__ y0, float* __restrict__ gpart) {
    __shared__ u16 xt[64 * CIN];          // B-tile [n][k] XOR-chunk-swizzled (24.5KB)
    __shared__ u16 ylds[CO * 64];         // y tile [o][n swz] (16KB)
    __shared__ float chs[CO], chq[CO];
    __shared__ int idxs[64];
    int tid = threadIdx.x;
    int l = tid & 63, w = tid >> 6, ln = l & 15, q = l >> 4;
    int b = blockIdx.x >> 7, n0 = (blockIdx.x & 127) << 6;
    if (tid < 64) idxs[tid] = idx[b * NN + n0 + tid];
    if (tid < 128) { chs[tid] = 0.f; chq[tid] = 0.f; }
    __syncthreads();
    // stage low_feats rows 0..63 via in-register transpose (lane = channel, f32 -> bf16)
    {
        const float* src = lf + (size_t)(b * C1 + l) * NN + n0 + (w << 4);
        float4 f0 = *(const float4*)src;
        float4 f1 = *(const float4*)(src + 4);
        float4 f2 = *(const float4*)(src + 8);
        float4 f3 = *(const float4*)(src + 12);
        float v[16] = {f0.x, f0.y, f0.z, f0.w, f1.x, f1.y, f1.z, f1.w,
                       f2.x, f2.y, f2.z, f2.w, f3.x, f3.y, f3.z, f3.w};
        int cc = l >> 3, clo = l & 7;
#pragma unroll
        for (int i = 0; i < 16; ++i) {
            int n = (w << 4) + i;
            xt[n * CIN + ((cc ^ (i & 7)) << 3) + clo] = f2b(v[i]);
        }
    }
    // gather nearest high rows (contiguous 256B per row from bf16 hT)
    for (int e = tid; e < 1024; e += 256) {
        int n = e >> 4, c16 = e & 15;
        uint4 v = *(const uint4*)(hT + (size_t)(b * MM + idxs[n]) * C2 + (c16 << 3));
        *(uint4*)&xt[n * CIN + (((8 + c16) ^ (n & 7)) << 3)] = v;
    }
    __syncthreads();
    f32x4 ac0[4], ac1[4];
#pragma unroll
    for (int nf = 0; nf < 4; ++nf) {
        ac0[nf] = f32x4{0.f, 0.f, 0.f, 0.f};
        ac1[nf] = f32x4{0.f, 0.f, 0.f, 0.f};
    }
    const u16* w0r0 = W0b + (32 * w + ln) * CIN + 8 * q;
    const u16* w0r1 = w0r0 + 16 * CIN;
#pragma unroll
    for (int s = 0; s < 6; ++s) {
        bf16x8 a0 = *(const bf16x8*)(w0r0 + 32 * s);
        bf16x8 a1 = *(const bf16x8*)(w0r1 + 32 * s);
#pragma unroll
        for (int nf = 0; nf < 4; ++nf) {
            bf16x8 bv = *(const bf16x8*)&xt[(16 * nf + ln) * CIN + (((4 * s + q) ^ (ln & 7)) << 3)];
            ac0[nf] = __builtin_amdgcn_mfma_f32_16x16x32_bf16(a0, bv, ac0[nf], 0, 0, 0);
            ac1[nf] = __builtin_amdgcn_mfma_f32_16x16x32_bf16(a1, bv, ac1[nf], 0, 0, 0);
        }
    }
    epilogue(ac0, ac1, b0, ylds, chs, chq, w, ln, q);
    __syncthreads();
    // per-block stat partials: unique coalesced slot, no global atomics
    gpart[blockIdx.x * 256 + tid] = (tid < 128) ? chs[tid] : chq[tid - 128];
    // coalesced store ylds -> y0 (ws, bf16)
    {
        int o = tid >> 1, h = tid & 1;
#pragma unroll
        for (int jj = 0; jj < 4; ++jj) {
            int j = (h << 2) + jj;
            uint4 v = *(const uint4*)&ylds[(o << 6) + ((j ^ (o & 7)) << 3)];
            *(uint4*)(y0 + (size_t)(b * CO + o) * NN + n0 + (j << 3)) = v;
        }
    }
}

// ---------------- layer 1: BN0+ReLU on y0 tile -> MFMA gemm -> y1pre in place + stat partials ----------------
__global__ __launch_bounds__(256) void k_l1(
        u16* __restrict__ y, const float* __restrict__ g0, const float* __restrict__ be0,
        const u16* __restrict__ W1b, const float* __restrict__ b1,
        const float* __restrict__ gstat, float* __restrict__ gpart) {
    __shared__ u16 xt[64 * CO];           // B-tile [n][k] swz (16KB)
    __shared__ u16 ylds[CO * 64];         // (16KB)
    __shared__ float chs[CO], chq[CO], sc[CO], sh[CO];
    int tid = threadIdx.x;
    int l = tid & 63, w = tid >> 6, ln = l & 15, q = l >> 4;
    int b = blockIdx.x >> 7, n0 = (blockIdx.x & 127) << 6;
    if (tid < 128) {
        float s = gstat[tid], qv = gstat[128 + tid];   // complete: dispatch boundary
        float mu = s * (1.f / NB);
        float var = qv * (1.f / NB) - mu * mu;
        float istd = 1.f / __fsqrt_rn(var + EPS);
        float scale = g0[tid] * istd;
        sc[tid] = scale;
        sh[tid] = be0[tid] - mu * scale;
        chs[tid] = 0.f; chq[tid] = 0.f;
    }
    __syncthreads();
    // stage y0 tile with BN0+ReLU via in-register transpose; 2 x 64 channels
#pragma unroll
    for (int it = 0; it < 2; ++it) {
        int c = (it << 6) + l;
        const u16* src = y + (size_t)(b * CO + c) * NN + n0 + (w << 4);
        uint4 r0 = *(const uint4*)src;
        uint4 r1 = *(const uint4*)(src + 8);
        u16 raw[16];
        *(uint4*)&raw[0] = r0;
        *(uint4*)&raw[8] = r1;
        float scale = sc[c], shift = sh[c];
        int cc = c >> 3, clo = c & 7;
#pragma unroll
        for (int i = 0; i < 16; ++i) {
            int n = (w << 4) + i;
            float hv = fmaxf(b2f(raw[i]) * scale + shift, 0.f);
            xt[(n << 7) + ((cc ^ (i & 7)) << 3) + clo] = f2b(hv);
        }
    }
    __syncthreads();
    f32x4 ac0[4], ac1[4];
#pragma unroll
    for (int nf = 0; nf < 4; ++nf) {
        ac0[nf] = f32x4{0.f, 0.f, 0.f, 0.f};
        ac1[nf] = f32x4{0.f, 0.f, 0.f, 0.f};
    }
    const u16* w1r0 = W1b + (32 * w + ln) * CO + 8 * q;
    const u16* w1r1 = w1r0 + 16 * CO;
#pragma unroll
    for (int s = 0; s < 4; ++s) {
        bf16x8 a0 = *(const bf16x8*)(w1r0 + 32 * s);
        bf16x8 a1 = *(const bf16x8*)(w1r1 + 32 * s);
#pragma unroll
        for (int nf = 0; nf < 4; ++nf) {
            bf16x8 bv = *(const bf16x8*)&xt[((16 * nf + ln) << 7) + (((4 * s + q) ^ (ln & 7)) << 3)];
            ac0[nf] = __builtin_amdgcn_mfma_f32_16x16x32_bf16(a0, bv, ac0[nf], 0, 0, 0);
            ac1[nf] = __builtin_amdgcn_mfma_f32_16x16x32_bf16(a1, bv, ac1[nf], 0, 0, 0);
        }
    }
    epilogue(ac0, ac1, b1, ylds, chs, chq, w, ln, q);
    __syncthreads();
    gpart[blockIdx.x * 256 + tid] = (tid < 128) ? chs[tid] : chq[tid - 128];
    // in-place store y1pre (bf16) over the same tile of ws
    {
        int o = tid >> 1, h = tid & 1;
#pragma unroll
        for (int jj = 0; jj < 4; ++jj) {
            int j = (h << 2) + jj;
            uint4 v = *(const uint4*)&ylds[(o << 6) + ((j ^ (o & 7)) << 3)];
            *(uint4*)(y + (size_t)(b * CO + o) * NN + n0 + (j << 3)) = v;
        }
    }
}

// ---------------- final BN1 + ReLU: y1pre (bf16, ws) -> d_out (f32) ----------------
__global__ __launch_bounds__(256) void k_bn1(
        const u16* __restrict__ y, const float* __restrict__ gstat,
        const float* __restrict__ g1, const float* __restrict__ be1,
        float* __restrict__ out) {
    int t = blockIdx.x * 256 + threadIdx.x;   // 4096 blocks: 8 elems/thread
    int o = (t >> 10) & 127;
    float s = gstat[256 + o], qv = gstat[384 + o];
    float mu = s * (1.f / NB);
    float var = qv * (1.f / NB) - mu * mu;
    float istd = 1.f / __fsqrt_rn(var + EPS);
    float scale = g1[o] * istd;
    float shift = be1[o] - mu * scale;
    size_t e0 = (size_t)t << 3;
    uint4 v = *(const uint4*)(y + e0);
    u16 raw[8];
    *(uint4*)raw = v;
    float r[8];
#pragma unroll
    for (int k = 0; k < 8; ++k)
        r[k] = fmaxf(b2f(raw[k]) * scale + shift, 0.f);
    *(float4*)(out + e0) = make_float4(r[0], r[1], r[2], r[3]);
    *(float4*)(out + e0 + 4) = make_float4(r[4], r[5], r[6], r[7]);
}

extern "C" void kernel_launch(void* const* d_in, const int* in_sizes, int n_in,
                              void* d_out, int out_size, void* d_ws, size_t ws_size,
                              hipStream_t stream) {
    const float* lt = (const float*)d_in[0];
    const float* lp = (const float*)d_in[1];
    const float* lf = (const float*)d_in[2];
    const float* ht = (const float*)d_in[3];
    const float* hp = (const float*)d_in[4];
    const float* hf = (const float*)d_in[5];
    const float* W0 = (const float*)d_in[6];
    const float* b0 = (const float*)d_in[7];
    const float* g0 = (const float*)d_in[8];
    const float* be0 = (const float*)d_in[9];
    const float* W1 = (const float*)d_in[10];
    const float* b1 = (const float*)d_in[11];
    const float* g1 = (const float*)d_in[12];
    const float* be1 = (const float*)d_in[13];

    char* ws = (char*)d_ws;
    u16* y0 = (u16*)ws;                         // 16.78 MB (y0, then y1pre in place)
    u16* hT = (u16*)(ws + 16777216);            // 4.19 MB
    int* idx = (int*)(ws + 20971520);           // 256 KB
    float* gstat = (float*)(ws + 21233664);     // 2 KB: [0:256]=L0 stats, [256:512]=L1
    u16* W0b = (u16*)(ws + 21235712);           // 48 KB
    u16* W1b = (u16*)(ws + 21284864);           // 32 KB
    float* gpart = (float*)(ws + 21317632);     // 1 MB per-block stat partials (reused)

    k_prep_w<<<96, 256, 0, stream>>>(W0, W1, W0b, W1b);
    k_prep_h<<<dim3(8, 32, 2), 256, 0, stream>>>(hf, hT);
    k_argmin<<<2048, 256, 0, stream>>>(lt, lp, ht, hp, idx);
    k_l0<<<1024, 256, 0, stream>>>(lf, hT, idx, W0b, b0, y0, gpart);
    k_red<<<256, 256, 0, stream>>>(gpart, gstat);
    k_l1<<<1024, 256, 0, stream>>>(y0, g0, be0, W1b, b1, gstat, gpart);
    k_red<<<256, 256, 0, stream>>>(gpart, gstat + 256);
    k_bn1<<<4096, 256, 0, stream>>>(y0, gstat, g1, be1, (float*)d_out);
}